// Round 1
// baseline (109.653 us; speedup 1.0000x reference)
//
#include <hip/hip_runtime.h>

#define NQ 10
#define EMBED 1024
#define ROWS_PER_BLOCK 16   // 4 waves x 4 rows
#define NR 4                // rows per wave

// RX-layer-2 partner XOR masks (index space, idx = lane*16 + slot),
// d_w = Linv(e_w) for the CNOT ring b1^=b0; b2^=b1; ... b0^=b9.
// lane-part (bits 4..9) and slot-part (bits 0..3):
//  w:      0     1     2     3     4     5     6    7    8    9
//  Lm:   0x30  0x18  0x0C  0x06  0x03  0x01  0x00 0x00 0x00 0x30
//  Sm:    0     0     0     0     0     8     0xC   6    3    1
// Sign masks for <Z_q> after the second (folded) ring: parity(p & M2[q]).
// (wire sets of L^2, mapped to bit positions pos = 9 - wire)

extern "C" __global__ __launch_bounds__(256, 2)
void ffq_kernel(const float* __restrict__ x, const float* __restrict__ W1,
                const float* __restrict__ b1, const float* __restrict__ qw,
                const float* __restrict__ W2, const float* __restrict__ b2,
                float* __restrict__ out)
{
    constexpr int M2[NQ] = {0x355,0x2FF,0x17F,0x2BF,0x15F,0x2AF,0x157,0x2AB,0x155,0x2AA};

    __shared__ float sW1[NQ * EMBED];          // 40 KiB
    __shared__ float sEV[ROWS_PER_BLOCK][NQ];  // tiny

    const int tid  = threadIdx.x;
    const int lane = tid & 63;
    const int wv   = tid >> 6;
    const int block0 = blockIdx.x * ROWS_PER_BLOCK;

    // ---- stage W1 into LDS (coalesced float4) ----
    {
        const float4* src = (const float4*)W1;
        float4* dst = (float4*)sW1;
        #pragma unroll
        for (int i = 0; i < 10; ++i) dst[tid + 256 * i] = src[tid + 256 * i];
    }
    __syncthreads();

    // ---- per-lane constants ----
    float qw0[NQ], b1r[NQ], fc[NQ], fs[NQ];
    #pragma unroll
    for (int w = 0; w < NQ; ++w) { qw0[w] = qw[w]; b1r[w] = b1[w]; }
    #pragma unroll
    for (int w = 0; w < NQ; ++w) {
        float h = qw[NQ + w] * 0.5f;
        fc[w] = __cosf(h);
        fs[w] = __sinf(h);
    }
    // lane-part of ev signs: idx bits 4..9 come from lane
    float ls[NQ];
    #pragma unroll
    for (int q = 0; q < NQ; ++q)
        ls[q] = (__popc((lane << 4) & M2[q]) & 1) ? -1.0f : 1.0f;

    for (int rr = 0; rr < NR; ++rr) {
        const int rlocal = wv * NR + rr;
        const int row = block0 + rlocal;

        // ---------- stage 1: ang[q] = dot(x_row, W1[q]) + b1[q] ----------
        float acc[NQ];
        #pragma unroll
        for (int q = 0; q < NQ; ++q) acc[q] = 0.f;
        const float4* xr = (const float4*)(x + (size_t)row * EMBED);
        #pragma unroll
        for (int c = 0; c < 4; ++c) {
            float4 xv = xr[c * 64 + lane];   // e = c*256 + lane*4 + k
            #pragma unroll
            for (int q = 0; q < NQ; ++q) {
                const float4 wv4 = *(const float4*)&sW1[q * EMBED + c * 256 + lane * 4];
                acc[q] = fmaf(xv.x, wv4.x, acc[q]);
                acc[q] = fmaf(xv.y, wv4.y, acc[q]);
                acc[q] = fmaf(xv.z, wv4.z, acc[q]);
                acc[q] = fmaf(xv.w, wv4.w, acc[q]);
            }
        }
        #pragma unroll
        for (int m = 1; m < 64; m <<= 1) {
            #pragma unroll
            for (int q = 0; q < NQ; ++q) acc[q] += __shfl_xor(acc[q], m, 64);
        }

        // merged first-RX angles: theta_w = ang_w + qweights[0][w]; half-angle cos/sin
        float cs[NQ], sn[NQ];
        #pragma unroll
        for (int w = 0; w < NQ; ++w) {
            float th = (acc[w] + b1r[w] + qw0[w]) * 0.5f;
            cs[w] = __cosf(th);
            sn[w] = __sinf(th);
        }

        // ---------- init product state ----------
        // idx = lane*16 + j ; lane bit b -> wire 5-b ; slot bit sb -> wire 9-sb
        float pb = 1.f;
        pb *= (lane & 1)  ? sn[5] : cs[5];
        pb *= (lane & 2)  ? sn[4] : cs[4];
        pb *= (lane & 4)  ? sn[3] : cs[3];
        pb *= (lane & 8)  ? sn[2] : cs[2];
        pb *= (lane & 16) ? sn[1] : cs[1];
        pb *= (lane & 32) ? sn[0] : cs[0];
        const int lpc = __popc(lane);

        float re[16], im[16];
        #pragma unroll
        for (int j = 0; j < 16; ++j) {
            float m = pb;
            m *= (j & 1) ? sn[9] : cs[9];
            m *= (j & 2) ? sn[8] : cs[8];
            m *= (j & 4) ? sn[7] : cs[7];
            m *= (j & 8) ? sn[6] : cs[6];
            const int k = (lpc + __popc(j)) & 3;   // (-i)^k
            const bool odd = k & 1;
            float v = (k & 2) ? -m : m;
            re[j] = odd ? 0.f : v;
            im[j] = odd ? -v : 0.f;
        }

        // ---------- RX layer 2, folded through ring 1 ----------
        // A[p] <- C*A[p] - i*S*A[p^d]
        #define RXG(LM, SM, CW, SW) do{                                        \
            float nre[16], nim[16];                                            \
            _Pragma("unroll")                                                  \
            for (int j = 0; j < 16; ++j) {                                     \
                float pre, pim;                                                \
                if ((LM) == 0) { pre = re[j ^ (SM)]; pim = im[j ^ (SM)]; }     \
                else { pre = __shfl_xor(re[j ^ (SM)], (LM), 64);               \
                       pim = __shfl_xor(im[j ^ (SM)], (LM), 64); }             \
                nre[j] = fmaf((CW), re[j],  (SW) * pim);                       \
                nim[j] = fmaf((CW), im[j], -(SW) * pre);                       \
            }                                                                  \
            _Pragma("unroll")                                                  \
            for (int j = 0; j < 16; ++j) { re[j] = nre[j]; im[j] = nim[j]; }   \
        } while(0)

        RXG(0x30, 0,   fc[0], fs[0]);
        RXG(0x18, 0,   fc[1], fs[1]);
        RXG(0x0C, 0,   fc[2], fs[2]);
        RXG(0x06, 0,   fc[3], fs[3]);
        RXG(0x03, 0,   fc[4], fs[4]);
        RXG(0x01, 8,   fc[5], fs[5]);
        RXG(0x00, 0xC, fc[6], fs[6]);
        RXG(0x00, 6,   fc[7], fs[7]);
        RXG(0x00, 3,   fc[8], fs[8]);
        RXG(0x30, 1,   fc[9], fs[9]);
        #undef RXG

        // ---------- ev_q = sum_p |A[p]|^2 * (+/-1), sign = parity(p & M2[q]) ----------
        float ev[NQ];
        #pragma unroll
        for (int q = 0; q < NQ; ++q) ev[q] = 0.f;
        #pragma unroll
        for (int j = 0; j < 16; ++j) {
            float p = re[j] * re[j] + im[j] * im[j];
            #pragma unroll
            for (int q = 0; q < NQ; ++q) {
                const bool neg = (__popc(j & M2[q]) & 1);   // compile-time
                ev[q] = fmaf(p, neg ? -ls[q] : ls[q], ev[q]);
            }
        }
        #pragma unroll
        for (int m = 1; m < 64; m <<= 1) {
            #pragma unroll
            for (int q = 0; q < NQ; ++q) ev[q] += __shfl_xor(ev[q], m, 64);
        }
        if (lane == 0) {
            #pragma unroll
            for (int q = 0; q < NQ; ++q) sEV[rlocal][q] = ev[q];
        }
    }

    __syncthreads();

    // ---------- stage 3: out[r][e] = b2[e] + sum_q ev[r][q]*W2[e][q] ----------
    // thread owns e0 = tid*4 .. tid*4+3 ; W2 rows in registers
    float w2f[40];
    {
        const float4* w2v = (const float4*)(W2 + tid * 40);
        #pragma unroll
        for (int i = 0; i < 10; ++i) {
            float4 v = w2v[i];
            w2f[4*i+0] = v.x; w2f[4*i+1] = v.y; w2f[4*i+2] = v.z; w2f[4*i+3] = v.w;
        }
    }
    const float4 b2v = ((const float4*)b2)[tid];

    #pragma unroll
    for (int r = 0; r < ROWS_PER_BLOCK; ++r) {
        float evr[NQ];
        #pragma unroll
        for (int q = 0; q < NQ; ++q) evr[q] = sEV[r][q];
        float o0 = b2v.x, o1 = b2v.y, o2 = b2v.z, o3 = b2v.w;
        #pragma unroll
        for (int q = 0; q < NQ; ++q) {
            o0 = fmaf(evr[q], w2f[ 0 + q], o0);
            o1 = fmaf(evr[q], w2f[10 + q], o1);
            o2 = fmaf(evr[q], w2f[20 + q], o2);
            o3 = fmaf(evr[q], w2f[30 + q], o3);
        }
        float4 o = {o0, o1, o2, o3};
        ((float4*)(out + (size_t)(block0 + r) * EMBED))[tid] = o;
    }
}

extern "C" void kernel_launch(void* const* d_in, const int* in_sizes, int n_in,
                              void* d_out, int out_size, void* d_ws, size_t ws_size,
                              hipStream_t stream) {
    (void)in_sizes; (void)n_in; (void)d_ws; (void)ws_size; (void)out_size;
    const float* x  = (const float*)d_in[0];
    const float* W1 = (const float*)d_in[1];
    const float* b1 = (const float*)d_in[2];
    const float* qw = (const float*)d_in[3];
    const float* W2 = (const float*)d_in[4];
    const float* b2 = (const float*)d_in[5];
    float* out = (float*)d_out;

    const int total_rows = 16 * 1024;                  // B*S
    dim3 grid(total_rows / ROWS_PER_BLOCK);            // 1024 blocks
    ffq_kernel<<<grid, 256, 0, stream>>>(x, W1, b1, qw, W2, b2, out);
}

// Round 2
// 37.990 us; speedup vs baseline: 2.8864x; 2.8864x over previous
//
#include <hip/hip_runtime.h>

#define NQ 10
#define EMBED 1024
#define ROWS_PER_BLOCK 16   // 4 waves x 4 rows
#define NR 4                // rows per wave

// ---------------------------------------------------------------------------
// Closed-form ev: conjugate circuit by H^10 -> RX gates become diagonal
// phases, CNOT ring becomes reversed ring sigma (b_i = a_i^a_{i+1}, i<9;
// b_9 = a_9^a_0^a_1).  State is a pure phase state; <Z_q> reduces to
//   ev_q = sum over S subset u_q with T=sigma^T S subset v_q of
//          i^(|T|+|S|) * prod_{w in T} sinA_w * prod_{v\T} cosA_w
//                      * prod_{w in S} sinB_w * prod_{u\S} cosB_w
// A_w = ang_w + qw[0][w], B_w = qw[1][w], u_q = sigma^-1 e_q, v_q = sigma^-2 e_q.
// Validated limits: qw1=0 -> prod_{v_q} cosA  (v_q == M2 masks of the
// previously passing state-sim kernel); A=0 -> prod_{u_q} cosB (== single-ring
// Heisenberg Z-masks).  Term list enumerated at compile time.
// ---------------------------------------------------------------------------

constexpr int kPop(int x) { int c = 0; for (int i = 0; i < 10; ++i) c += (x >> i) & 1; return c; }

constexpr int sigma_map(int a) {
    int b = 0;
    for (int i = 0; i < 9; ++i) b |= (((a >> i) & 1) ^ ((a >> (i + 1)) & 1)) << i;
    b |= (((a >> 9) & 1) ^ ((a >> 0) & 1) ^ ((a >> 1) & 1)) << 9;
    return b;
}

#define MAXT 40
struct Terms {
    int nt[NQ];
    int vm[NQ];
    int um[NQ];
    unsigned short tm[NQ][MAXT];
    unsigned short sm[NQ][MAXT];
    float sg[NQ][MAXT];
};

constexpr Terms gen_terms() {
    Terms t{};
    int inv_e[NQ] = {};
    for (int a = 0; a < 1024; ++a) {
        const int s = sigma_map(a);
        for (int q = 0; q < NQ; ++q) if (s == (1 << q)) inv_e[q] = a;
    }
    for (int q = 0; q < NQ; ++q) {
        const int u = inv_e[q];
        int v = 0;
        for (int w = 0; w < NQ; ++w) if ((u >> w) & 1) v ^= inv_e[w];
        t.um[q] = u; t.vm[q] = v;
        int n = 0;
        int S = 0;
        while (true) {
            int T = (((S >> 0) ^ (S >> 9)) & 1)
                  | ((((S >> 0) ^ (S >> 1) ^ (S >> 9)) & 1) << 1);
            for (int j = 2; j < 10; ++j) T |= ((((S >> (j - 1)) ^ (S >> j)) & 1) << j);
            if ((T & ~v) == 0) {
                const int p = kPop(T) + kPop(S);
                t.tm[q][n] = (unsigned short)T;
                t.sm[q][n] = (unsigned short)S;
                t.sg[q][n] = (p & 1) ? 0.f : ((p & 2) ? -1.f : 1.f);
                ++n;
            }
            if (S == u) break;
            S = (S - u) & u;   // next subset of u
        }
        t.nt[q] = n;
    }
    return t;
}

constexpr Terms TT = gen_terms();

extern "C" __global__ __launch_bounds__(256, 2)
void ffq_kernel(const float* __restrict__ x, const float* __restrict__ W1,
                const float* __restrict__ b1, const float* __restrict__ qw,
                const float* __restrict__ W2, const float* __restrict__ b2,
                float* __restrict__ out)
{
    __shared__ float sW1[NQ * EMBED];           // 40 KiB
    __shared__ float sANG[ROWS_PER_BLOCK][12];  // full angles A_w per row
    __shared__ float sEV[ROWS_PER_BLOCK][NQ];

    const int tid  = threadIdx.x;
    const int lane = tid & 63;
    const int wv   = tid >> 6;
    const int block0 = blockIdx.x * ROWS_PER_BLOCK;

    // ---- stage W1 into LDS (coalesced float4) ----
    {
        const float4* src = (const float4*)W1;
        float4* dst = (float4*)sW1;
        #pragma unroll
        for (int i = 0; i < 10; ++i) dst[tid + 256 * i] = src[tid + 256 * i];
    }
    __syncthreads();

    float qw0[NQ], b1r[NQ];
    #pragma unroll
    for (int w = 0; w < NQ; ++w) { qw0[w] = qw[w]; b1r[w] = b1[w]; }

    for (int rr = 0; rr < NR; ++rr) {
        const int rlocal = wv * NR + rr;
        const int row = block0 + rlocal;

        // ---------- stage 1: ang[q] = dot(x_row, W1[q]) ----------
        float acc[NQ];
        #pragma unroll
        for (int q = 0; q < NQ; ++q) acc[q] = 0.f;
        const float4* xr = (const float4*)(x + (size_t)row * EMBED);
        #pragma unroll
        for (int c = 0; c < 4; ++c) {
            float4 xv = xr[c * 64 + lane];
            #pragma unroll
            for (int q = 0; q < NQ; ++q) {
                const float4 wv4 = *(const float4*)&sW1[q * EMBED + c * 256 + lane * 4];
                acc[q] = fmaf(xv.x, wv4.x, acc[q]);
                acc[q] = fmaf(xv.y, wv4.y, acc[q]);
                acc[q] = fmaf(xv.z, wv4.z, acc[q]);
                acc[q] = fmaf(xv.w, wv4.w, acc[q]);
            }
        }
        #pragma unroll
        for (int m = 1; m < 64; m <<= 1) {
            #pragma unroll
            for (int q = 0; q < NQ; ++q) acc[q] += __shfl_xor(acc[q], m, 64);
        }
        if (lane == 0) {
            #pragma unroll
            for (int w = 0; w < NQ; ++w) sANG[rlocal][w] = acc[w] + b1r[w] + qw0[w];
        }
    }

    __syncthreads();

    // ---------- closed-form ev: one row per lane (lanes 0..15 of wave 0) ----
    if (tid < ROWS_PER_BLOCK) {
        float ca[NQ], sa[NQ], cb[NQ], sb[NQ];
        #pragma unroll
        for (int w = 0; w < NQ; ++w) {
            const float A = sANG[tid][w];
            ca[w] = __cosf(A); sa[w] = __sinf(A);
            const float B = qw[NQ + w];
            cb[w] = __cosf(B); sb[w] = __sinf(B);
        }
        #pragma unroll
        for (int q = 0; q < NQ; ++q) {
            float ev = 0.f;
            #pragma unroll
            for (int k = 0; k < TT.nt[q]; ++k) {
                float P = TT.sg[q][k];
                #pragma unroll
                for (int w = 0; w < NQ; ++w) {
                    if ((TT.vm[q] >> w) & 1) P *= ((TT.tm[q][k] >> w) & 1) ? sa[w] : ca[w];
                    if ((TT.um[q] >> w) & 1) P *= ((TT.sm[q][k] >> w) & 1) ? sb[w] : cb[w];
                }
                ev += P;
            }
            sEV[tid][q] = ev;
        }
    }

    __syncthreads();

    // ---------- stage 3: out[r][e] = b2[e] + sum_q ev[r][q]*W2[e][q] ----------
    float w2f[40];
    {
        const float4* w2v = (const float4*)(W2 + tid * 40);
        #pragma unroll
        for (int i = 0; i < 10; ++i) {
            float4 v = w2v[i];
            w2f[4*i+0] = v.x; w2f[4*i+1] = v.y; w2f[4*i+2] = v.z; w2f[4*i+3] = v.w;
        }
    }
    const float4 b2v = ((const float4*)b2)[tid];

    #pragma unroll
    for (int r = 0; r < ROWS_PER_BLOCK; ++r) {
        float evr[NQ];
        #pragma unroll
        for (int q = 0; q < NQ; ++q) evr[q] = sEV[r][q];
        float o0 = b2v.x, o1 = b2v.y, o2 = b2v.z, o3 = b2v.w;
        #pragma unroll
        for (int q = 0; q < NQ; ++q) {
            o0 = fmaf(evr[q], w2f[ 0 + q], o0);
            o1 = fmaf(evr[q], w2f[10 + q], o1);
            o2 = fmaf(evr[q], w2f[20 + q], o2);
            o3 = fmaf(evr[q], w2f[30 + q], o3);
        }
        float4 o = {o0, o1, o2, o3};
        ((float4*)(out + (size_t)(block0 + r) * EMBED))[tid] = o;
    }
}

extern "C" void kernel_launch(void* const* d_in, const int* in_sizes, int n_in,
                              void* d_out, int out_size, void* d_ws, size_t ws_size,
                              hipStream_t stream) {
    (void)in_sizes; (void)n_in; (void)d_ws; (void)ws_size; (void)out_size;
    const float* x  = (const float*)d_in[0];
    const float* W1 = (const float*)d_in[1];
    const float* b1 = (const float*)d_in[2];
    const float* qw = (const float*)d_in[3];
    const float* W2 = (const float*)d_in[4];
    const float* b2 = (const float*)d_in[5];
    float* out = (float*)d_out;

    const int total_rows = 16 * 1024;
    dim3 grid(total_rows / ROWS_PER_BLOCK);
    ffq_kernel<<<grid, 256, 0, stream>>>(x, W1, b1, qw, W2, b2, out);
}

// Round 3
// 31.511 us; speedup vs baseline: 3.4798x; 1.2056x over previous
//
#include <hip/hip_runtime.h>

#define NQ 10
#define EMBED 1024
#define ROWS_PER_BLOCK 32   // 8 waves x 4 simultaneous rows
#define BLOCK 512

// ---------------------------------------------------------------------------
// Closed-form ev (validated in R1/R2, passing at absmax 2e-3):
// conjugate circuit by H^10 -> RX gates become diagonal phases, CNOT ring
// becomes reversed ring sigma.  <Z_q> collapses to a trig polynomial:
//   ev_q = sum_{S subset u_q, T=sigma^T S subset v_q} i^(|T|+|S|)
//          prod_{T} sinA prod_{v\T} cosA * prod_{S} sinB prod_{u\S} cosB
// A_w = ang_w + qw[0][w], B_w = qw[1][w], u_q = sigma^-1 e_q, v_q = sigma^-2 e_q.
// Odd-parity (sg==0) terms are pure-imaginary and cancel -> filtered here
// at constexpr time (provably adds zero vs the passing R2 kernel).
// ---------------------------------------------------------------------------

constexpr int kPop(int x) { int c = 0; for (int i = 0; i < 10; ++i) c += (x >> i) & 1; return c; }

constexpr int sigma_map(int a) {
    int b = 0;
    for (int i = 0; i < 9; ++i) b |= (((a >> i) & 1) ^ ((a >> (i + 1)) & 1)) << i;
    b |= (((a >> 9) & 1) ^ ((a >> 0) & 1) ^ ((a >> 1) & 1)) << 9;
    return b;
}

#define MAXT 40
struct Terms {
    int nt[NQ];
    int vm[NQ];
    int um[NQ];
    unsigned short tm[NQ][MAXT];
    unsigned short sm[NQ][MAXT];
    float sg[NQ][MAXT];
};

constexpr Terms gen_terms() {
    Terms t{};
    int inv_e[NQ] = {};
    for (int a = 0; a < 1024; ++a) {
        const int s = sigma_map(a);
        for (int q = 0; q < NQ; ++q) if (s == (1 << q)) inv_e[q] = a;
    }
    for (int q = 0; q < NQ; ++q) {
        const int u = inv_e[q];
        int v = 0;
        for (int w = 0; w < NQ; ++w) if ((u >> w) & 1) v ^= inv_e[w];
        t.um[q] = u; t.vm[q] = v;
        int n = 0;
        int S = 0;
        while (true) {
            int T = (((S >> 0) ^ (S >> 9)) & 1)
                  | ((((S >> 0) ^ (S >> 1) ^ (S >> 9)) & 1) << 1);
            for (int j = 2; j < 10; ++j) T |= ((((S >> (j - 1)) ^ (S >> j)) & 1) << j);
            if ((T & ~v) == 0) {
                const int p = kPop(T) + kPop(S);
                if (!(p & 1)) {               // drop zero (imaginary) terms
                    t.tm[q][n] = (unsigned short)T;
                    t.sm[q][n] = (unsigned short)S;
                    t.sg[q][n] = (p & 2) ? -1.f : 1.f;
                    ++n;
                }
            }
            if (S == u) break;
            S = (S - u) & u;   // next subset of u
        }
        t.nt[q] = n;
    }
    return t;
}

constexpr Terms TT = gen_terms();

extern "C" __global__ __launch_bounds__(BLOCK, 4)
void ffq_kernel(const float* __restrict__ x, const float* __restrict__ W1,
                const float* __restrict__ b1, const float* __restrict__ qw,
                const float* __restrict__ W2, const float* __restrict__ b2,
                float* __restrict__ out)
{
    __shared__ float sW1[NQ * EMBED];             // 40 KiB
    __shared__ float sCA[ROWS_PER_BLOCK][NQ];     // cos(A_w) per row
    __shared__ float sSA[ROWS_PER_BLOCK][NQ];     // sin(A_w) per row
    __shared__ float sEV[ROWS_PER_BLOCK][NQ];

    const int tid  = threadIdx.x;
    const int lane = tid & 63;
    const int wv   = tid >> 6;          // 0..7
    const int o    = lane & 15;         // lane-in-group
    const int g    = lane >> 4;         // group 0..3 (one row each)
    const int block0 = blockIdx.x * ROWS_PER_BLOCK;

    // ---- stage W1 into LDS (coalesced float4) ----
    {
        const float4* src = (const float4*)W1;
        float4* dst = (float4*)sW1;
        #pragma unroll
        for (int i = 0; i < 5; ++i) dst[tid + BLOCK * i] = src[tid + BLOCK * i];
    }

    float b1r[NQ], qw0[NQ];
    #pragma unroll
    for (int w = 0; w < NQ; ++w) { qw0[w] = qw[w]; b1r[w] = b1[w]; }

    __syncthreads();

    // ---------- stage 1: 4 rows per wave, 16 lanes per row ----------
    {
        const int rloc = wv * 4 + g;
        const int row  = block0 + rloc;
        float acc[NQ];
        #pragma unroll
        for (int q = 0; q < NQ; ++q) acc[q] = 0.f;

        const float4* xr  = (const float4*)(x + (size_t)row * EMBED);
        const float4* w1v = (const float4*)sW1;
        #pragma unroll 4
        for (int k = 0; k < 16; ++k) {
            const float4 xv = xr[k * 16 + o];
            #pragma unroll
            for (int q = 0; q < NQ; ++q) {
                const float4 wv4 = w1v[q * 256 + k * 16 + o];  // broadcast x4 groups
                acc[q] = fmaf(xv.x, wv4.x, acc[q]);
                acc[q] = fmaf(xv.y, wv4.y, acc[q]);
                acc[q] = fmaf(xv.z, wv4.z, acc[q]);
                acc[q] = fmaf(xv.w, wv4.w, acc[q]);
            }
        }
        // reduce across the 16 lanes of the group
        #pragma unroll
        for (int m = 1; m < 16; m <<= 1) {
            #pragma unroll
            for (int q = 0; q < NQ; ++q) acc[q] += __shfl_xor(acc[q], m, 64);
        }
        if (o == 0) {
            #pragma unroll
            for (int w = 0; w < NQ; ++w) {
                const float A = acc[w] + b1r[w] + qw0[w];
                sCA[rloc][w] = __cosf(A);
                sSA[rloc][w] = __sinf(A);
            }
        }
    }

    __syncthreads();

    // ---------- closed-form ev: wave0 -> q{0,9}, wave1 -> q{1..8} ----------
    if (wv < 2 && lane < ROWS_PER_BLOCK) {
        const int row = lane;
        float ca[NQ], sa[NQ], cb[NQ], sb[NQ];
        #pragma unroll
        for (int w = 0; w < NQ; ++w) {
            ca[w] = sCA[row][w];
            sa[w] = sSA[row][w];
            const float B = qw[NQ + w];
            cb[w] = __cosf(B); sb[w] = __sinf(B);
        }
        #define EVQ(QC) do {                                                      \
            float ev = 0.f;                                                       \
            _Pragma("unroll")                                                     \
            for (int k = 0; k < TT.nt[QC]; ++k) {                                 \
                float P = TT.sg[QC][k];                                           \
                _Pragma("unroll")                                                 \
                for (int w = 0; w < NQ; ++w) {                                    \
                    if ((TT.vm[QC] >> w) & 1) P *= ((TT.tm[QC][k] >> w) & 1) ? sa[w] : ca[w]; \
                    if ((TT.um[QC] >> w) & 1) P *= ((TT.sm[QC][k] >> w) & 1) ? sb[w] : cb[w]; \
                }                                                                 \
                ev += P;                                                          \
            }                                                                     \
            sEV[row][QC] = ev;                                                    \
        } while (0)
        if (wv == 0) { EVQ(0); EVQ(9); }
        else         { EVQ(1); EVQ(2); EVQ(3); EVQ(4); EVQ(5); EVQ(6); EVQ(7); EVQ(8); }
        #undef EVQ
    }

    __syncthreads();

    // ---------- stage 3: out[r][e] = b2[e] + sum_q ev[r][q]*W2[e][q] ----------
    // 512 threads: e4 = tid&255 (float4 column), half = tid>>8 (16 rows each)
    const int e4 = tid & 255;
    const int r0 = (tid >> 8) * 16;

    float w2f[40];
    {
        const float4* w2v = (const float4*)(W2 + e4 * 40);
        #pragma unroll
        for (int i = 0; i < 10; ++i) {
            float4 v = w2v[i];
            w2f[4*i+0] = v.x; w2f[4*i+1] = v.y; w2f[4*i+2] = v.z; w2f[4*i+3] = v.w;
        }
    }
    const float4 b2v = ((const float4*)b2)[e4];

    #pragma unroll
    for (int r = 0; r < 16; ++r) {
        const int rr = r0 + r;
        float evr[NQ];
        #pragma unroll
        for (int q = 0; q < NQ; ++q) evr[q] = sEV[rr][q];
        float o0 = b2v.x, o1 = b2v.y, o2 = b2v.z, o3 = b2v.w;
        #pragma unroll
        for (int q = 0; q < NQ; ++q) {
            o0 = fmaf(evr[q], w2f[ 0 + q], o0);
            o1 = fmaf(evr[q], w2f[10 + q], o1);
            o2 = fmaf(evr[q], w2f[20 + q], o2);
            o3 = fmaf(evr[q], w2f[30 + q], o3);
        }
        float4 ov = {o0, o1, o2, o3};
        ((float4*)(out + (size_t)(block0 + rr) * EMBED))[e4] = ov;
    }
}

extern "C" void kernel_launch(void* const* d_in, const int* in_sizes, int n_in,
                              void* d_out, int out_size, void* d_ws, size_t ws_size,
                              hipStream_t stream) {
    (void)in_sizes; (void)n_in; (void)d_ws; (void)ws_size; (void)out_size;
    const float* x  = (const float*)d_in[0];
    const float* W1 = (const float*)d_in[1];
    const float* b1 = (const float*)d_in[2];
    const float* qw = (const float*)d_in[3];
    const float* W2 = (const float*)d_in[4];
    const float* b2 = (const float*)d_in[5];
    float* out = (float*)d_out;

    const int total_rows = 16 * 1024;
    dim3 grid(total_rows / ROWS_PER_BLOCK);   // 512 blocks, 2/CU, zero tail
    ffq_kernel<<<grid, BLOCK, 0, stream>>>(x, W1, b1, qw, W2, b2, out);
}